// Round 1
// baseline (8536.607 us; speedup 1.0000x reference)
//
#include <hip/hip_runtime.h>
#include <cstdint>
#include <cstddef>

// Model constants
static constexpr int kD   = 768;
static constexpr int kHD  = 64;
static constexpr int kNH  = 12;
static constexpr int kT   = 512;
static constexpr int kB   = 4;
static constexpr int kRows = kB * kT;        // 2048
static constexpr int kV   = 50257;
static constexpr int kL   = 6;
static constexpr int kFF  = 3072;
static constexpr float kEps = 1e-5f;

// ---------------------------------------------------------------------------
// Embedding: x[row,d] = tok_emb[ids[row], d] + pos_emb[row % T, d]
// ---------------------------------------------------------------------------
__global__ __launch_bounds__(256) void embed_kernel(
    const int* __restrict__ ids, const float* __restrict__ tok,
    const float* __restrict__ pos, float* __restrict__ x)
{
    int i = blockIdx.x * 256 + threadIdx.x;
    if (i >= kRows * kD) return;
    int row = i / kD, d = i - row * kD;
    x[i] = tok[(size_t)ids[row] * kD + d] + pos[(row % kT) * kD + d];
}

// ---------------------------------------------------------------------------
// LayerNorm: one block (256 threads) per row of 768
// ---------------------------------------------------------------------------
__global__ __launch_bounds__(256) void ln_kernel(
    const float* __restrict__ x, const float* __restrict__ g,
    const float* __restrict__ b, float* __restrict__ o)
{
    const int row = blockIdx.x;
    const float* xr = x + (size_t)row * kD;
    float s = 0.f, ss = 0.f;
    for (int d = threadIdx.x; d < kD; d += 256) {
        float v = xr[d];
        s += v; ss += v * v;
    }
    #pragma unroll
    for (int off = 32; off; off >>= 1) {
        s  += __shfl_xor(s, off);
        ss += __shfl_xor(ss, off);
    }
    __shared__ float sh_s[4], sh_ss[4];
    const int wid = threadIdx.x >> 6, lane = threadIdx.x & 63;
    if (lane == 0) { sh_s[wid] = s; sh_ss[wid] = ss; }
    __syncthreads();
    s  = sh_s[0] + sh_s[1] + sh_s[2] + sh_s[3];
    ss = sh_ss[0] + sh_ss[1] + sh_ss[2] + sh_ss[3];
    const float mean = s * (1.0f / kD);
    const float var  = ss * (1.0f / kD) - mean * mean;
    const float rstd = rsqrtf(var + kEps);
    float* orow = o + (size_t)row * kD;
    for (int d = threadIdx.x; d < kD; d += 256)
        orow[d] = (xr[d] - mean) * rstd * g[d] + b[d];
}

// ---------------------------------------------------------------------------
// Repack per-layer QKV weights (H,D,HD each) into W [768 x 2304] and bias[2304]
// column c: c/768 selects K/Q/V, (c%768) = h*64+e
// ---------------------------------------------------------------------------
__global__ __launch_bounds__(256) void repack_qkv_kernel(
    const float* __restrict__ wk, const float* __restrict__ wq,
    const float* __restrict__ wv, const float* __restrict__ bk,
    const float* __restrict__ bq, const float* __restrict__ bv,
    float* __restrict__ Wp, float* __restrict__ Bp)
{
    int i = blockIdx.x * 256 + threadIdx.x;
    if (i < 3 * kD) {
        int which = i / kD, c = i - which * kD;
        const float* bsrc = (which == 0) ? bk : (which == 1) ? bq : bv;
        Bp[i] = bsrc[c];
    }
    if (i >= kD * 3 * kD) return;
    int col = i % (3 * kD), d = i / (3 * kD);
    int which = col / kD, hc = col - which * kD;   // hc = h*64+e
    const float* src = (which == 0) ? wk : (which == 1) ? wq : wv;
    // src layout (H, D, HD): h*D*HD + d*HD + e
    Wp[i] = src[(size_t)(hc >> 6) * (kD * kHD) + (size_t)d * kHD + (hc & 63)];
}

// ---------------------------------------------------------------------------
// Generic fp32 tiled GEMM: out[M,N] = A[M,K] @ W[K,N] (+bias) (+resid) (relu?)
// 64x64 tile, BK=16, 256 threads, 4x4 per thread. M % 64 == 0, K % 16 == 0.
// N may be ragged (logits).
// ---------------------------------------------------------------------------
__global__ __launch_bounds__(256) void gemm_kernel(
    const float* __restrict__ A, const float* __restrict__ W,
    const float* __restrict__ bias, const float* __restrict__ resid,
    float* __restrict__ out, int M, int N, int K, int relu)
{
    __shared__ float As[16][68];   // transposed A tile, padded (+4 keeps 16B align)
    __shared__ float Bs[16][64];
    const int tid = threadIdx.x;
    const int m0 = blockIdx.y * 64;
    const int n0 = blockIdx.x * 64;
    const int ty = tid >> 4, tx = tid & 15;
    const int arow = tid >> 2, akc = (tid & 3) << 2;
    const int brow = tid >> 4, bcol = (tid & 15) << 2;
    const bool nal = ((N & 3) == 0);
    float acc[4][4] = {{0.f, 0.f, 0.f, 0.f}, {0.f, 0.f, 0.f, 0.f},
                       {0.f, 0.f, 0.f, 0.f}, {0.f, 0.f, 0.f, 0.f}};
    for (int k0 = 0; k0 < K; k0 += 16) {
        float4 av = *(const float4*)(A + (size_t)(m0 + arow) * K + (k0 + akc));
        As[akc + 0][arow] = av.x;
        As[akc + 1][arow] = av.y;
        As[akc + 2][arow] = av.z;
        As[akc + 3][arow] = av.w;
        float4 bvv;
        const size_t wb = (size_t)(k0 + brow) * N + n0 + bcol;
        if (nal && (n0 + bcol + 3 < N)) {
            bvv = *(const float4*)(W + wb);
        } else {
            bvv.x = (n0 + bcol + 0 < N) ? W[wb + 0] : 0.f;
            bvv.y = (n0 + bcol + 1 < N) ? W[wb + 1] : 0.f;
            bvv.z = (n0 + bcol + 2 < N) ? W[wb + 2] : 0.f;
            bvv.w = (n0 + bcol + 3 < N) ? W[wb + 3] : 0.f;
        }
        *(float4*)&Bs[brow][bcol] = bvv;
        __syncthreads();
        #pragma unroll
        for (int k = 0; k < 16; ++k) {
            float4 a4 = *(const float4*)&As[k][ty << 2];
            float4 b4 = *(const float4*)&Bs[k][tx << 2];
            float a[4] = {a4.x, a4.y, a4.z, a4.w};
            float b[4] = {b4.x, b4.y, b4.z, b4.w};
            #pragma unroll
            for (int i = 0; i < 4; ++i)
                #pragma unroll
                for (int j = 0; j < 4; ++j)
                    acc[i][j] = fmaf(a[i], b[j], acc[i][j]);
        }
        __syncthreads();
    }
    #pragma unroll
    for (int i = 0; i < 4; ++i) {
        const int m = m0 + (ty << 2) + i;
        #pragma unroll
        for (int j = 0; j < 4; ++j) {
            const int n = n0 + (tx << 2) + j;
            if (n < N) {
                float v = acc[i][j];
                if (bias)  v += bias[n];
                if (resid) v += resid[(size_t)m * N + n];
                if (relu)  v = fmaxf(v, 0.f);
                out[(size_t)m * N + n] = v;
            }
        }
    }
}

// ---------------------------------------------------------------------------
// Attention: one 64-thread block per (b, h, t).
// qkv layout: [row=b*T+s][2304] with K at cols 0..767, Q at 768.., V at 1536..
// Quirk preserved: wei[t][s] = k_t . q_s (k indexes rows!), no 1/sqrt(d).
// ---------------------------------------------------------------------------
__global__ __launch_bounds__(64) void attn_kernel(
    const float* __restrict__ qkv, float* __restrict__ out)
{
    const int t = blockIdx.x, h = blockIdx.y, b = blockIdx.z;
    const int tid = threadIdx.x;
    __shared__ float kt[64];
    __shared__ float sc[kT];
    const size_t rowbase = ((size_t)b * kT + t) * (3 * kD);
    kt[tid] = qkv[rowbase + h * kHD + tid];
    __syncthreads();
    float lmax = -INFINITY;
    for (int s = tid; s <= t; s += 64) {
        const float* qr = qkv + ((size_t)b * kT + s) * (3 * kD) + kD + h * kHD;
        float a = 0.f;
        #pragma unroll
        for (int e = 0; e < 64; ++e) a = fmaf(kt[e], qr[e], a);
        sc[s] = a;
        lmax = fmaxf(lmax, a);
    }
    #pragma unroll
    for (int off = 32; off; off >>= 1) lmax = fmaxf(lmax, __shfl_xor(lmax, off));
    float lsum = 0.f;
    for (int s = tid; s <= t; s += 64) {
        float p = __expf(sc[s] - lmax);
        sc[s] = p;
        lsum += p;
    }
    #pragma unroll
    for (int off = 32; off; off >>= 1) lsum += __shfl_xor(lsum, off);
    __syncthreads();
    const float inv = 1.0f / lsum;
    float acc = 0.f;
    const float* vbase = qkv + (size_t)b * kT * (3 * kD) + 2 * kD + h * kHD + tid;
    for (int s = 0; s <= t; ++s)
        acc = fmaf(sc[s], vbase[(size_t)s * (3 * kD)], acc);
    out[((size_t)b * kT + t) * kD + h * kHD + tid] = acc * inv;
}

// ---------------------------------------------------------------------------
// Loss: one block per row; logsumexp over V, nll = logZ - logit[target]
// ---------------------------------------------------------------------------
__global__ __launch_bounds__(256) void loss_kernel(
    const float* __restrict__ logits, const int* __restrict__ target,
    float* __restrict__ loss)
{
    const int row = blockIdx.x;
    const float* lr = logits + (size_t)row * kV;
    const int wid = threadIdx.x >> 6, lane = threadIdx.x & 63;
    __shared__ float red[4];

    float lmax = -INFINITY;
    for (int i = threadIdx.x; i < kV; i += 256) lmax = fmaxf(lmax, lr[i]);
    #pragma unroll
    for (int off = 32; off; off >>= 1) lmax = fmaxf(lmax, __shfl_xor(lmax, off));
    if (lane == 0) red[wid] = lmax;
    __syncthreads();
    lmax = fmaxf(fmaxf(red[0], red[1]), fmaxf(red[2], red[3]));
    __syncthreads();

    float lsum = 0.f;
    for (int i = threadIdx.x; i < kV; i += 256) lsum += __expf(lr[i] - lmax);
    #pragma unroll
    for (int off = 32; off; off >>= 1) lsum += __shfl_xor(lsum, off);
    if (lane == 0) red[wid] = lsum;
    __syncthreads();
    lsum = red[0] + red[1] + red[2] + red[3];

    if (threadIdx.x == 0) {
        float logZ = lmax + logf(lsum);
        float nll = logZ - lr[target[row]];
        atomicAdd(loss, nll * (1.0f / kRows));
    }
}

// ---------------------------------------------------------------------------
static inline void launch_gemm(const float* A, const float* W, const float* bias,
                               const float* resid, float* out, int M, int N,
                               int K, int relu, hipStream_t stream)
{
    dim3 grid((N + 63) / 64, M / 64);
    gemm_kernel<<<grid, 256, 0, stream>>>(A, W, bias, resid, out, M, N, K, relu);
}

extern "C" void kernel_launch(void* const* d_in, const int* in_sizes, int n_in,
                              void* d_out, int out_size, void* d_ws, size_t ws_size,
                              hipStream_t stream)
{
    const int*   ids = (const int*)d_in[0];
    const int*   tgt = (const int*)d_in[1];
    const float* tok = (const float*)d_in[2];
    const float* pos = (const float*)d_in[3];
    const float* ipw = (const float*)d_in[4];
    const float* ipb = (const float*)d_in[5];
    const float* wk  = (const float*)d_in[6];
    const float* bk  = (const float*)d_in[7];
    const float* wq  = (const float*)d_in[8];
    const float* bq  = (const float*)d_in[9];
    const float* wv  = (const float*)d_in[10];
    const float* bv  = (const float*)d_in[11];
    const float* opw = (const float*)d_in[12];
    const float* opb = (const float*)d_in[13];
    const float* fw1 = (const float*)d_in[14];
    const float* fb1 = (const float*)d_in[15];
    const float* fw2 = (const float*)d_in[16];
    const float* fb2 = (const float*)d_in[17];
    const float* lag = (const float*)d_in[18];
    const float* lab = (const float*)d_in[19];
    const float* lfg = (const float*)d_in[20];
    const float* lfb = (const float*)d_in[21];
    const float* outw = (const float*)d_in[22];
    const float* outb = (const float*)d_in[23];

    float* ws = (float*)d_ws;
    float* x    = ws;                       // 2048*768
    float* h    = x    + (size_t)kRows * kD;
    float* h2   = h    + (size_t)kRows * kD;
    float* atb  = h2   + (size_t)kRows * kD;
    float* qkv  = atb  + (size_t)kRows * kD;        // 2048*2304
    float* ffh  = qkv  + (size_t)kRows * 3 * kD;    // 2048*3072
    float* wqkv = ffh  + (size_t)kRows * kFF;       // 768*2304
    float* bqkv = wqkv + (size_t)kD * 3 * kD;       // 2304

    float* logits = (float*)d_out;
    float* loss = logits + (size_t)kRows * kV;

    embed_kernel<<<(kRows * kD + 255) / 256, 256, 0, stream>>>(ids, tok, pos, x);

    const size_t wsz = (size_t)kD * kD;          // 589824 (== H*D*HD too)
    const size_t fsz = (size_t)kD * kFF;         // 2359296
    for (int l = 0; l < kL; ++l) {
        ln_kernel<<<kRows, 256, 0, stream>>>(x, lag + l * kD, lab + l * kD, h);
        launch_gemm(h, ipw + l * wsz, ipb + l * kD, nullptr, h2,
                    kRows, kD, kD, 0, stream);
        repack_qkv_kernel<<<(kD * 3 * kD + 255) / 256, 256, 0, stream>>>(
            wk + l * wsz, wq + l * wsz, wv + l * wsz,
            bk + l * kD, bq + l * kD, bv + l * kD, wqkv, bqkv);
        launch_gemm(h2, wqkv, bqkv, nullptr, qkv, kRows, 3 * kD, kD, 0, stream);
        attn_kernel<<<dim3(kT, kNH, kB), 64, 0, stream>>>(qkv, atb);
        launch_gemm(atb, opw + l * wsz, opb + l * kD, x, x,
                    kRows, kD, kD, 0, stream);
        ln_kernel<<<kRows, 256, 0, stream>>>(x, lfg + l * kD, lfb + l * kD, h);
        launch_gemm(h, fw1 + l * fsz, fb1 + l * kFF, nullptr, ffh,
                    kRows, kFF, kD, 1, stream);
        launch_gemm(ffh, fw2 + l * fsz, fb2 + l * kD, x, x,
                    kRows, kD, kFF, 0, stream);
    }
    launch_gemm(x, outw, outb, nullptr, logits, kRows, kV, kD, 0, stream);
    hipMemsetAsync(loss, 0, sizeof(float), stream);
    loss_kernel<<<kRows, 256, 0, stream>>>(logits, tgt, loss);
}